// Round 16
// baseline (1173.182 us; speedup 1.0000x reference)
//
#include <hip/hip_runtime.h>
#include <stdint.h>

// ---------------------------------------------------------------------------
// DecoderLSTM: B=32, S=128, H=1024, L=2, V=32000, teacher forcing (tf=1)
//
// Round 16 (micro-opts on the round-15 fused structure):
//   (a) per-WAVE producer slots: each fusion wave publishes its slot right
//       after its own s_waitcnt vmcnt(0) -> removes the producer-side
//       __syncthreads + tid0-only store from the handoff critical path.
//   (b) zx0 loads issued BEFORE the poll (latency hides under the wait).
//   (c) merged small launches (one w_ih cvt, one init kernel).
// Structure otherwise identical to round 15 (recurrence 192 WGs + 64 proj
// workers, gated job queue, t-major outb, permuted-C epilogue, ws-rich
// path with round-14-style fallback).
// ---------------------------------------------------------------------------

typedef __attribute__((ext_vector_type(8))) short short8;
typedef __attribute__((ext_vector_type(4))) float f32x4;

#define MFMA16(a, b, c) __builtin_amdgcn_mfma_f32_16x16x32_bf16((a), (b), (c), 0, 0, 0)

__device__ __forceinline__ unsigned short f2bf(float f) {
  union { float f; unsigned int u; } v; v.f = f;
  unsigned int u = v.u;
  return (unsigned short)((u + 0x7fffu + ((u >> 16) & 1u)) >> 16);
}

__device__ __forceinline__ void gload_lds16(const unsigned short* g, unsigned short* l) {
  __builtin_amdgcn_global_load_lds(
      (const __attribute__((address_space(1))) void*)g,
      (__attribute__((address_space(3))) void*)l, 16, 0, 0);
}

__device__ __forceinline__ void st_u32_dev(unsigned* p, unsigned v) {
  __hip_atomic_store(p, v, __ATOMIC_RELAXED, __HIP_MEMORY_SCOPE_AGENT);
}
__device__ __forceinline__ unsigned ld_u32_dev(const unsigned* p) {
  return __hip_atomic_load(p, __ATOMIC_RELAXED, __HIP_MEMORY_SCOPE_AGENT);
}

// ---- conversion / small kernels -------------------------------------------

__global__ void cvt_bf16_k(const float* __restrict__ s, unsigned short* __restrict__ d, int n4) {
  int i = blockIdx.x * blockDim.x + threadIdx.x;
  int st = gridDim.x * blockDim.x;
  for (; i < n4; i += st) {
    float4 v = ((const float4*)s)[i];
    ushort4 o;
    o.x = f2bf(v.x); o.y = f2bf(v.y); o.z = f2bf(v.z); o.w = f2bf(v.w);
    ((ushort4*)d)[i] = o;
  }
}

// blocks 0..31: h0 cvt; 32..63: h1init cvt; 64..95: bsum
__global__ void init_small_k(const float* __restrict__ hidden,
                             const float* __restrict__ b_ih, const float* __restrict__ b_hh,
                             unsigned short* __restrict__ h0, unsigned short* __restrict__ h1,
                             float* __restrict__ bsum) {
  int bb = blockIdx.x;
  int tid = threadIdx.x;
  if (bb < 64) {
    const float* src = hidden + (bb < 32 ? 0 : 32768);
    unsigned short* dst = (bb < 32) ? h0 : h1;
    int i = (bb & 31) * 256 + tid;          // 8192 float4 per half
    float4 v = ((const float4*)src)[i];
    ushort4 u;
    u.x = f2bf(v.x); u.y = f2bf(v.y); u.z = f2bf(v.z); u.w = f2bf(v.w);
    ((ushort4*)dst)[i] = u;
  } else {
    int i = (bb - 64) * 256 + tid;          // 8192 floats
    bsum[i] = b_ih[i] + b_hh[i];
  }
}

__global__ void embed_k(const int* __restrict__ x, const int* __restrict__ tgt,
                        const float* __restrict__ emb, unsigned short* __restrict__ xseq) {
  int row = blockIdx.x;          // t*32 + b
  int t = row >> 5, b = row & 31;
  int tok = (t == 0) ? x[b] : tgt[b * 128 + t];
  const float4* e = (const float4*)(emb + (size_t)tok * 1024);
  ushort4* o = (ushort4*)(xseq + (size_t)row * 1024);
  int i = threadIdx.x;
  float4 v = e[i];
  ushort4 u;
  u.x = f2bf(v.x); u.y = f2bf(v.y); u.z = f2bf(v.z); u.w = f2bf(v.w);
  o[i] = u;
}

// ---- bf16 MFMA GEMM (round-11 pipelined; + permC flag) --------------------

__global__ __launch_bounds__(256, 2) void gemm_bf16_k(
    const unsigned short* __restrict__ A, const unsigned short* __restrict__ B,
    float* __restrict__ C, const float* __restrict__ bias, int N, int permC) {
  __shared__ __align__(16) unsigned short smem[32768];
  const int tid = threadIdx.x;
  const int lane = tid & 63;
  const int w = tid >> 6;
  const int wm = w >> 1, wn = w & 1;
  const int xcd = blockIdx.x & 7;
  const int idx = blockIdx.x >> 3;
  const int nBase = (idx >> 2) * 128;
  const int mBase = (xcd * 4 + (idx & 3)) * 128;
  const int lr = lane & 15, lk = lane >> 4;
  const int K = 1024;

  const int srow = tid >> 3;
  const int scol = (tid & 7) ^ (srow & 7);
  const int wchunk = tid & 192;

  f32x4 acc[4][4];
#pragma unroll
  for (int i = 0; i < 4; ++i)
#pragma unroll
    for (int j = 0; j < 4; ++j) acc[i][j] = (f32x4){0.f, 0.f, 0.f, 0.f};

  const unsigned short* Ag = A + (size_t)mBase * K;
  const unsigned short* Bg = B + (size_t)nBase * K;

  auto stage = [&](int buf, int kt) {
    unsigned short* Ab = smem + buf * 16384;
    unsigned short* Bb = Ab + 8192;
#pragma unroll
    for (int r = 0; r < 4; ++r) {
      int row = r * 32 + srow;
      gload_lds16(Ag + (size_t)row * K + kt * 64 + scol * 8, &Ab[(r * 256 + wchunk) * 8]);
      gload_lds16(Bg + (size_t)row * K + kt * 64 + scol * 8, &Bb[(r * 256 + wchunk) * 8]);
    }
  };

  stage(0, 0);
  __syncthreads();
  for (int kt = 0; kt < 16; ++kt) {
    int cur = kt & 1;
    if (kt < 15) stage(cur ^ 1, kt + 1);
    const unsigned short* Ac = smem + cur * 16384;
    const unsigned short* Bc = Ac + 8192;
#pragma unroll
    for (int ks = 0; ks < 2; ++ks) {
      short8 a[4], b[4];
#pragma unroll
      for (int mf = 0; mf < 4; ++mf) {
        int row = wm * 64 + mf * 16 + lr;
        int cc = (ks * 4 + lk) ^ (row & 7);
        a[mf] = *(const short8*)&Ac[row * 64 + cc * 8];
      }
#pragma unroll
      for (int nf = 0; nf < 4; ++nf) {
        int row = wn * 64 + nf * 16 + lr;
        int cc = (ks * 4 + lk) ^ (row & 7);
        b[nf] = *(const short8*)&Bc[row * 64 + cc * 8];
      }
#pragma unroll
      for (int mf = 0; mf < 4; ++mf)
#pragma unroll
        for (int nf = 0; nf < 4; ++nf)
          acc[mf][nf] = MFMA16(a[mf], b[nf], acc[mf][nf]);
    }
    __syncthreads();
  }

  float* cst = (float*)smem;
#pragma unroll
  for (int r = 0; r < 4; ++r) {
    __syncthreads();
#pragma unroll
    for (int nf = 0; nf < 4; ++nf) {
      int col = wn * 64 + nf * 16 + lr;
      float bv = bias ? bias[nBase + col] : 0.f;
#pragma unroll
      for (int i = 0; i < 4; ++i)
        cst[(wm * 16 + lk * 4 + i) * 132 + col] = acc[r][nf][i] + bv;
    }
    __syncthreads();
#pragma unroll
    for (int pss = 0; pss < 4; ++pss) {
      int idxq = pss * 256 + tid;
      int rl = idxq >> 5, cq = idxq & 31;
      int ar = mBase + (rl >> 4) * 64 + r * 16 + (rl & 15);
      int cr = permC ? ((ar & 31) * 128 + (ar >> 5)) : ar;
      f32x4 v = *(const f32x4*)&cst[rl * 132 + cq * 4];
      __builtin_nontemporal_store(v, (f32x4*)&C[(size_t)cr * N + nBase + cq * 4]);
    }
  }
}

// ---- persistent recurrence + fused gated proj -----------------------------
// Per-wave slots: slots0[wg*32 + w] (w=0..3, L0); slots1[wg*32 + w] (w=0..1).

struct PParams {
  const float* zx0;
  const unsigned short* whh0;
  const unsigned short* wih1;
  const unsigned short* whh1;
  const float* bsum1;
  const float* cell;
  unsigned short* h0hist;       // [129][32][1024]
  const unsigned short* h1init; // [32][1024]
  unsigned short* outb;         // [128][32][1024]  t-major
  unsigned int* slots0;         // 64 WGs x 32-uint blocks (waves 0..3 used)
  unsigned int* slots1;         // 128 WGs x 32-uint blocks (waves 0..1 used)
  unsigned int* queue;
  const unsigned short* embB;
  float* outC;
  int njobs;
};

__device__ __forceinline__ bool l0_ready(const unsigned* slots0, int lane, unsigned tgt) {
  const unsigned* blk = slots0 + lane * 32;
  bool ok = ld_u32_dev(blk + 0) >= tgt && ld_u32_dev(blk + 1) >= tgt &&
            ld_u32_dev(blk + 2) >= tgt && ld_u32_dev(blk + 3) >= tgt;
  return ok;
}
__device__ __forceinline__ bool l1_ready(const unsigned* slots1, int lane, unsigned tgt) {
  const unsigned* a = slots1 + lane * 32;
  const unsigned* b = slots1 + (lane + 64) * 32;
  return ld_u32_dev(a) >= tgt && ld_u32_dev(a + 1) >= tgt &&
         ld_u32_dev(b) >= tgt && ld_u32_dev(b + 1) >= tgt;
}

__device__ __forceinline__ void proj_tile(int j, bool valid, int ltid, char* smbase,
                                          const unsigned short* Aout,
                                          const unsigned short* Bemb, float* C) {
  const int mB = j / 250, nB = j % 250;
  const int mBase = mB * 128, nBase = nB * 128;
  const int lane = ltid & 63;
  const int w4 = ltid >> 6;
  const int wm = w4 >> 1, wn = w4 & 1;
  const int lr = lane & 15, lk = lane >> 4;
  const int srow = ltid >> 3;
  const int scol = (ltid & 7) ^ (srow & 7);
  const int wchunk = ltid & 192;
  unsigned short* smem = (unsigned short*)smbase;

  f32x4 acc[4][4];
#pragma unroll
  for (int i = 0; i < 4; ++i)
#pragma unroll
    for (int q = 0; q < 4; ++q) acc[i][q] = (f32x4){0.f, 0.f, 0.f, 0.f};

  const unsigned short* Ag = Aout + (size_t)mBase * 1024;
  const unsigned short* Bg = Bemb + (size_t)nBase * 1024;

  auto stage = [&](int buf, int kt) {
    if (!valid) return;
    unsigned short* Ab = smem + buf * 16384;
    unsigned short* Bb = Ab + 8192;
#pragma unroll
    for (int r = 0; r < 4; ++r) {
      int row = r * 32 + srow;
      gload_lds16(Ag + (size_t)row * 1024 + kt * 64 + scol * 8, &Ab[(r * 256 + wchunk) * 8]);
      gload_lds16(Bg + (size_t)row * 1024 + kt * 64 + scol * 8, &Bb[(r * 256 + wchunk) * 8]);
    }
  };

  stage(0, 0);
  __syncthreads();
  for (int kt = 0; kt < 16; ++kt) {
    int cur = kt & 1;
    if (kt < 15) stage(cur ^ 1, kt + 1);
    const unsigned short* Ac = smem + cur * 16384;
    const unsigned short* Bc = Ac + 8192;
    if (valid) {
#pragma unroll
      for (int ks = 0; ks < 2; ++ks) {
        short8 a[4], b[4];
#pragma unroll
        for (int mf = 0; mf < 4; ++mf) {
          int row = wm * 64 + mf * 16 + lr;
          int cc = (ks * 4 + lk) ^ (row & 7);
          a[mf] = *(const short8*)&Ac[row * 64 + cc * 8];
        }
#pragma unroll
        for (int nf = 0; nf < 4; ++nf) {
          int row = wn * 64 + nf * 16 + lr;
          int cc = (ks * 4 + lk) ^ (row & 7);
          b[nf] = *(const short8*)&Bc[row * 64 + cc * 8];
        }
#pragma unroll
        for (int mf = 0; mf < 4; ++mf)
#pragma unroll
          for (int nf = 0; nf < 4; ++nf)
            acc[mf][nf] = MFMA16(a[mf], b[nf], acc[mf][nf]);
      }
    }
    __syncthreads();
  }

  float* cst = (float*)smem;
#pragma unroll
  for (int r = 0; r < 4; ++r) {
    __syncthreads();
    if (valid) {
#pragma unroll
      for (int nf = 0; nf < 4; ++nf) {
        int col = wn * 64 + nf * 16 + lr;
#pragma unroll
        for (int i = 0; i < 4; ++i)
          cst[(wm * 16 + lk * 4 + i) * 132 + col] = acc[r][nf][i];
      }
    }
    __syncthreads();
    if (valid) {
#pragma unroll
      for (int pss = 0; pss < 4; ++pss) {
        int idxq = pss * 256 + ltid;
        int rl = idxq >> 5, cq = idxq & 31;
        int ar = mBase + (rl >> 4) * 64 + r * 16 + (rl & 15);
        int cr = (ar & 31) * 128 + (ar >> 5);
        f32x4 v = *(const f32x4*)&cst[rl * 132 + cq * 4];
        __builtin_nontemporal_store(v, (f32x4*)&C[(size_t)cr * 32000 + nBase + cq * 4]);
      }
    }
  }
}

__global__ __launch_bounds__(512, 1) void lstm_persist_k(PParams P) {
  const int tid = threadIdx.x;
  const int lane = tid & 63;
  const int w = tid >> 6;
  const int lr = lane & 15, lkk = lane >> 4;

  __shared__ __align__(16) char pool[149504];
  __shared__ int jbase;
  unsigned short* wlds = (unsigned short*)pool;
  float* zraw = (float*)(pool + 131072);

  if (blockIdx.x < 64) {
    // ---------------- layer 0: units u0..u0+15 ----------------
    const int u0 = blockIdx.x * 16;
    const int m = w >> 2;
    const int gp = (w >> 1) & 1;
    const int kh = w & 1;
    const int g0 = gp * 2, g1 = gp * 2 + 1;

    for (int f = w; f < 128; f += 8) {
      int gg = f >> 5, kc = f & 31;
      const unsigned short* src =
          P.whh0 + (size_t)(gg * 1024 + u0 + lr) * 1024 + kc * 32 + lkk * 8;
      *(short8*)&wlds[f * 512 + lane * 8] = *(const short8*)src;
    }
    const int fb = tid >> 3;
    const int jp = tid & 7;
    float creg[2] = {0.f, 0.f};
    if (tid < 256) {
      creg[0] = P.cell[fb * 1024 + u0 + 2 * jp];
      creg[1] = P.cell[fb * 1024 + u0 + 2 * jp + 1];
    }
    __syncthreads();

    for (int i = 0; i < 128; ++i) {
      // zx0 prefetch BEFORE the poll: latency hides under the wait
      float2 zr[4];
      if (tid < 256) {
        const float2* br = (const float2*)(P.zx0 + (size_t)i * 131072 + fb * 4096 + u0 + 2 * jp);
#pragma unroll
        for (int q = 0; q < 4; ++q) zr[q] = br[q * 512];
      }
      if (i > 0 && tid < 64) {
        const unsigned tgt = (unsigned)i;
        while (!l0_ready(P.slots0, tid, tgt)) __builtin_amdgcn_s_sleep(1);
      }
      __syncthreads();

      f32x4 acc0 = {0.f, 0.f, 0.f, 0.f}, acc1 = {0.f, 0.f, 0.f, 0.f};
      const unsigned short* ap =
          P.h0hist + (size_t)i * 32768 + (size_t)(m * 16 + lr) * 1024 + kh * 512 + lkk * 8;
#pragma unroll
      for (int g4 = 0; g4 < 2; ++g4) {
        short8 a[8];
#pragma unroll
        for (int q = 0; q < 8; ++q) a[q] = *(const short8*)(ap + (g4 * 8 + q) * 32);
#pragma unroll
        for (int q = 0; q < 8; ++q) {
          int kc = kh * 16 + g4 * 8 + q;
          short8 b0 = *(const short8*)&wlds[(g0 * 32 + kc) * 512 + lane * 8];
          short8 b1 = *(const short8*)&wlds[(g1 * 32 + kc) * 512 + lane * 8];
          acc0 = MFMA16(a[q], b0, acc0);
          acc1 = MFMA16(a[q], b1, acc1);
        }
      }
#pragma unroll
      for (int j = 0; j < 4; ++j) {
        zraw[(kh * 32 + m * 16 + lkk * 4 + j) * 72 + g0 * 16 + lr] = acc0[j];
        zraw[(kh * 32 + m * 16 + lkk * 4 + j) * 72 + g1 * 16 + lr] = acc1[j];
      }
      __syncthreads();

      if (tid < 256) {
        unsigned hv = 0;
#pragma unroll
        for (int u = 0; u < 2; ++u) {
          int j = 2 * jp + u;
          float zi = zraw[fb * 72 + j]      + zraw[(32 + fb) * 72 + j]      + ((u == 0) ? zr[0].x : zr[0].y);
          float zf = zraw[fb * 72 + 16 + j] + zraw[(32 + fb) * 72 + 16 + j] + ((u == 0) ? zr[1].x : zr[1].y);
          float zg = zraw[fb * 72 + 32 + j] + zraw[(32 + fb) * 72 + 32 + j] + ((u == 0) ? zr[2].x : zr[2].y);
          float zo = zraw[fb * 72 + 48 + j] + zraw[(32 + fb) * 72 + 48 + j] + ((u == 0) ? zr[3].x : zr[3].y);
          float ii = 1.f / (1.f + __expf(-zi));
          float ff = 1.f / (1.f + __expf(-zf));
          float gg = tanhf(zg);
          float oo = 1.f / (1.f + __expf(-zo));
          float cn = ff * creg[u] + ii * gg;
          creg[u] = cn;
          float hn = oo * tanhf(cn);
          hv |= ((unsigned)f2bf(hn)) << (16 * u);
        }
        st_u32_dev((unsigned*)&P.h0hist[(size_t)(i + 1) * 32768 + fb * 1024 + u0 + 2 * jp], hv);
        // per-wave publish: this wave's h stores ACK'd -> store its slot
        asm volatile("s_waitcnt vmcnt(0)" ::: "memory");
        if (lane == 0) st_u32_dev(&P.slots0[blockIdx.x * 32 + w], (unsigned)(i + 1));
      }
      // no producer-side barrier: next-iteration post-poll barrier orders zraw reuse
    }
  } else if (blockIdx.x < 192) {
    // ---------------- layer 1: units u0..u0+7 ----------------
    const int u0 = (blockIdx.x - 64) * 8;
    const int slot = blockIdx.x - 64;
    const int mat = w >> 2;
    const int m = (w >> 1) & 1;
    const int kh = w & 1;

    for (int f = w; f < 128; f += 8) {
      int matf = f >> 6, nt = (f >> 5) & 1, kc = f & 31;
      int rr = nt * 16 + lr;
      int gate = rr >> 3, unit = rr & 7;
      const unsigned short* Wm = matf ? P.whh1 : P.wih1;
      const unsigned short* src =
          Wm + (size_t)(gate * 1024 + u0 + unit) * 1024 + kc * 32 + lkk * 8;
      *(short8*)&wlds[f * 512 + lane * 8] = *(const short8*)src;
    }
    const int fb = tid >> 2;
    const int jp = tid & 3;
    float creg[2] = {0.f, 0.f};
    float brg[4][2];
    if (tid < 128) {
      creg[0] = P.cell[32768 + fb * 1024 + u0 + 2 * jp];
      creg[1] = P.cell[32768 + fb * 1024 + u0 + 2 * jp + 1];
#pragma unroll
      for (int q = 0; q < 4; ++q) {
        brg[q][0] = P.bsum1[q * 1024 + u0 + 2 * jp];
        brg[q][1] = P.bsum1[q * 1024 + u0 + 2 * jp + 1];
      }
    }
    __syncthreads();

    for (int i = 1; i <= 128; ++i) {
      if (tid < 64) {
        const unsigned t0 = (unsigned)i, t1 = (unsigned)(i - 1);
        while (true) {
          bool ok = l0_ready(P.slots0, tid, t0);
          if (i > 1) ok = ok && l1_ready(P.slots1, tid, t1);
          if (__all(ok)) break;
          __builtin_amdgcn_s_sleep(2);
        }
      }
      __syncthreads();

      f32x4 acc0 = {0.f, 0.f, 0.f, 0.f}, acc1 = {0.f, 0.f, 0.f, 0.f};
      const unsigned short* ap;
      if (mat == 0) {
        ap = P.h0hist + (size_t)i * 32768 + (size_t)(m * 16 + lr) * 1024 + kh * 512 + lkk * 8;
      } else {
        const unsigned short* h1b =
            (i == 1) ? P.h1init : (P.outb + (size_t)(i - 2) * 32768);
        ap = h1b + (size_t)(m * 16 + lr) * 1024 + kh * 512 + lkk * 8;
      }
#pragma unroll
      for (int g4 = 0; g4 < 2; ++g4) {
        short8 a[8];
#pragma unroll
        for (int q = 0; q < 8; ++q) a[q] = *(const short8*)(ap + (g4 * 8 + q) * 32);
#pragma unroll
        for (int q = 0; q < 8; ++q) {
          int kc = kh * 16 + g4 * 8 + q;
          short8 b0 = *(const short8*)&wlds[(mat * 64 + 0 * 32 + kc) * 512 + lane * 8];
          short8 b1 = *(const short8*)&wlds[(mat * 64 + 1 * 32 + kc) * 512 + lane * 8];
          acc0 = MFMA16(a[q], b0, acc0);
          acc1 = MFMA16(a[q], b1, acc1);
        }
      }
      float* zp = zraw + (mat * 2 + kh) * 1152;
#pragma unroll
      for (int j = 0; j < 4; ++j) {
        zp[(m * 16 + lkk * 4 + j) * 36 + lr] = acc0[j];
        zp[(m * 16 + lkk * 4 + j) * 36 + 16 + lr] = acc1[j];
      }
      __syncthreads();

      if (tid < 128) {
        unsigned hv = 0;
#pragma unroll
        for (int u = 0; u < 2; ++u) {
          int j = 2 * jp + u;
          float z4[4];
#pragma unroll
          for (int q = 0; q < 4; ++q) {
            z4[q] = zraw[fb * 36 + q * 8 + j] + zraw[1152 + fb * 36 + q * 8 + j]
                  + zraw[2304 + fb * 36 + q * 8 + j] + zraw[3456 + fb * 36 + q * 8 + j]
                  + brg[q][u];
          }
          float ii = 1.f / (1.f + __expf(-z4[0]));
          float ff = 1.f / (1.f + __expf(-z4[1]));
          float gg = tanhf(z4[2]);
          float oo = 1.f / (1.f + __expf(-z4[3]));
          float cn = ff * creg[u] + ii * gg;
          creg[u] = cn;
          float hn = oo * tanhf(cn);
          hv |= ((unsigned)f2bf(hn)) << (16 * u);
        }
        st_u32_dev((unsigned*)&P.outb[(size_t)(i - 1) * 32768 + fb * 1024 + u0 + 2 * jp], hv);
        asm volatile("s_waitcnt vmcnt(0)" ::: "memory");
        if (lane == 0) st_u32_dev(&P.slots1[slot * 32 + w], (unsigned)i);
      }
    }
  }

  // ---------------- gated proj job loop (2 tiles per WG) ----------------
  while (true) {
    __syncthreads();
    if (tid == 0)
      jbase = (int)__hip_atomic_fetch_add(P.queue, 2u, __ATOMIC_RELAXED,
                                          __HIP_MEMORY_SCOPE_AGENT);
    __syncthreads();
    int base = jbase;
    if (base >= P.njobs) break;
    int j = base + (tid >> 8);
    bool valid = (j < P.njobs);
    int jmax = (base + 1 < P.njobs) ? base + 1 : base;
    int gateMB = jmax / 250;
    if (tid < 64) {
      unsigned tgt = (unsigned)(4 * gateMB + 4);
      if (tgt > 128u) tgt = 128u;
      while (!l1_ready(P.slots1, tid, tgt)) __builtin_amdgcn_s_sleep(2);
    }
    __syncthreads();
    proj_tile(j, valid, tid & 255, pool + (tid >> 8) * 65536, P.outb, P.embB, P.outC);
  }
}

// ---------------------------------------------------------------------------

extern "C" void kernel_launch(void* const* d_in, const int* in_sizes, int n_in,
                              void* d_out, int out_size, void* d_ws, size_t ws_size,
                              hipStream_t stream) {
  const int*   x      = (const int*)d_in[0];
  const float* hidden = (const float*)d_in[1];
  const float* cell   = (const float*)d_in[2];
  const int*   target = (const int*)d_in[3];
  const float* emb    = (const float*)d_in[5];
  const float* w_ih   = (const float*)d_in[6];
  const float* w_hh   = (const float*)d_in[7];
  const float* b_ih   = (const float*)d_in[8];
  const float* b_hh   = (const float*)d_in[9];
  float* out = (float*)d_out;
  char* ws = (char*)d_ws;

  // ws layout (bytes)
  unsigned short* emb_bf  = (unsigned short*)(ws);                 // 65,536,000
  unsigned short* wih_bf  = (unsigned short*)(ws + 65536000);      // 16,777,216 (L0+L1)
  unsigned short* whh_bf  = (unsigned short*)(ws + 82313216);      // 16,777,216 (L0+L1)
  float*          bsum    = (float*)(ws + 99090432);               //     32,768
  unsigned short* outb    = (unsigned short*)(ws + 99123200);      //  8,388,608 (t-major)
  unsigned int*   barmem  = (unsigned int*)(ws + 107511808);       //     32,768
  unsigned short* h1init  = (unsigned short*)(ws + 107544576);     //     65,536

  const size_t WS_NEED = 107610112ull + 67108864ull + 8454144ull;  // 183,173,120
  const bool rich = (ws_size >= WS_NEED);
  float*          zx0    = rich ? (float*)(ws + 107610112)
                                : (float*)d_out;
  unsigned short* xseq   = rich ? (unsigned short*)d_out
                                : (unsigned short*)((char*)d_out + 67108864);
  unsigned short* h0hist = rich ? (unsigned short*)(ws + 174718976)
                                : (unsigned short*)((char*)d_out + 75497472);

  hipMemsetAsync(barmem, 0, 32768, stream);
  cvt_bf16_k<<<2048, 256, 0, stream>>>(emb, emb_bf, 8192000);
  cvt_bf16_k<<<2048, 256, 0, stream>>>(w_ih, wih_bf, 2097152);     // both layers
  cvt_bf16_k<<<2048, 256, 0, stream>>>(w_hh, whh_bf, 2097152);     // both layers
  init_small_k<<<96, 256, 0, stream>>>(hidden, b_ih, b_hh, h0hist, h1init, bsum);
  embed_k<<<4096, 256, 0, stream>>>(x, target, emb, xseq);

  // Zx0 = x_seq @ w_ih[0]^T + bsum0   [4096 x 4096]
  gemm_bf16_k<<<1024, 256, 0, stream>>>(xseq, wih_bf, zx0, bsum, 4096, 0);

  PParams pp;
  pp.zx0 = zx0;
  pp.whh0 = whh_bf;
  pp.wih1 = wih_bf + 4194304;
  pp.whh1 = whh_bf + 4194304;
  pp.bsum1 = bsum + 4096;
  pp.cell = cell;
  pp.h0hist = h0hist;
  pp.h1init = h1init;
  pp.outb = outb;
  pp.slots0 = barmem;              // 64 x 32-uint blocks
  pp.slots1 = barmem + 2048;       // 128 x 32-uint blocks
  pp.queue = barmem + 6144;
  pp.embB = emb_bf;
  pp.outC = out;
  pp.njobs = rich ? 8000 : 0;
  lstm_persist_k<<<rich ? 256 : 192, 512, 0, stream>>>(pp);

  if (!rich) {
    gemm_bf16_k<<<8000, 256, 0, stream>>>(outb, emb_bf, out, nullptr, 32000, 1);
  }
}

// Round 17
// 1081.135 us; speedup vs baseline: 1.0851x; 1.0851x over previous
//
#include <hip/hip_runtime.h>
#include <stdint.h>

// ---------------------------------------------------------------------------
// DecoderLSTM: B=32, S=128, H=1024, L=2, V=32000, teacher forcing (tf=1)
//
// Round 17 = round 15 persist protocol (proven best: 1084us total) + R16's
// safe launch merges. R16's per-wave slots + barrier removal regressed
// (1015 -> 1115us persist): wider poll set + straggling publishes cost more
// than the producer barrier they removed.
//
// Structure:
//   - pre: cvts (merged), embed, Zx0 GEMM (2-phase pipelined, XCD-mapped)
//   - ONE fused persistent kernel: 192 recurrence WGs (slot-synced,
//     fence-free cacheable reads, LDS weights, K-split waves) + 64 proj
//     workers on a gated job queue (t-major outb, 4t/M-tile gating);
//     recurrence WGs join the proj queue when done.
//   - ws-rich path (zx0/h0hist in ws); round-14-style fallback otherwise.
// ---------------------------------------------------------------------------

typedef __attribute__((ext_vector_type(8))) short short8;
typedef __attribute__((ext_vector_type(4))) float f32x4;

#define MFMA16(a, b, c) __builtin_amdgcn_mfma_f32_16x16x32_bf16((a), (b), (c), 0, 0, 0)

__device__ __forceinline__ unsigned short f2bf(float f) {
  union { float f; unsigned int u; } v; v.f = f;
  unsigned int u = v.u;
  return (unsigned short)((u + 0x7fffu + ((u >> 16) & 1u)) >> 16);
}

__device__ __forceinline__ void gload_lds16(const unsigned short* g, unsigned short* l) {
  __builtin_amdgcn_global_load_lds(
      (const __attribute__((address_space(1))) void*)g,
      (__attribute__((address_space(3))) void*)l, 16, 0, 0);
}

__device__ __forceinline__ void st_u32_dev(unsigned* p, unsigned v) {
  __hip_atomic_store(p, v, __ATOMIC_RELAXED, __HIP_MEMORY_SCOPE_AGENT);
}
__device__ __forceinline__ unsigned ld_u32_dev(const unsigned* p) {
  return __hip_atomic_load(p, __ATOMIC_RELAXED, __HIP_MEMORY_SCOPE_AGENT);
}

// ---- conversion / small kernels -------------------------------------------

__global__ void cvt_bf16_k(const float* __restrict__ s, unsigned short* __restrict__ d, int n4) {
  int i = blockIdx.x * blockDim.x + threadIdx.x;
  int st = gridDim.x * blockDim.x;
  for (; i < n4; i += st) {
    float4 v = ((const float4*)s)[i];
    ushort4 o;
    o.x = f2bf(v.x); o.y = f2bf(v.y); o.z = f2bf(v.z); o.w = f2bf(v.w);
    ((ushort4*)d)[i] = o;
  }
}

// blocks 0..31: h0 cvt; 32..63: h1init cvt; 64..95: bsum
__global__ void init_small_k(const float* __restrict__ hidden,
                             const float* __restrict__ b_ih, const float* __restrict__ b_hh,
                             unsigned short* __restrict__ h0, unsigned short* __restrict__ h1,
                             float* __restrict__ bsum) {
  int bb = blockIdx.x;
  int tid = threadIdx.x;
  if (bb < 64) {
    const float* src = hidden + (bb < 32 ? 0 : 32768);
    unsigned short* dst = (bb < 32) ? h0 : h1;
    int i = (bb & 31) * 256 + tid;
    float4 v = ((const float4*)src)[i];
    ushort4 u;
    u.x = f2bf(v.x); u.y = f2bf(v.y); u.z = f2bf(v.z); u.w = f2bf(v.w);
    ((ushort4*)dst)[i] = u;
  } else {
    int i = (bb - 64) * 256 + tid;
    bsum[i] = b_ih[i] + b_hh[i];
  }
}

__global__ void embed_k(const int* __restrict__ x, const int* __restrict__ tgt,
                        const float* __restrict__ emb, unsigned short* __restrict__ xseq) {
  int row = blockIdx.x;          // t*32 + b
  int t = row >> 5, b = row & 31;
  int tok = (t == 0) ? x[b] : tgt[b * 128 + t];
  const float4* e = (const float4*)(emb + (size_t)tok * 1024);
  ushort4* o = (ushort4*)(xseq + (size_t)row * 1024);
  int i = threadIdx.x;
  float4 v = e[i];
  ushort4 u;
  u.x = f2bf(v.x); u.y = f2bf(v.y); u.z = f2bf(v.z); u.w = f2bf(v.w);
  o[i] = u;
}

// ---- bf16 MFMA GEMM (round-11 pipelined; + permC flag) --------------------

__global__ __launch_bounds__(256, 2) void gemm_bf16_k(
    const unsigned short* __restrict__ A, const unsigned short* __restrict__ B,
    float* __restrict__ C, const float* __restrict__ bias, int N, int permC) {
  __shared__ __align__(16) unsigned short smem[32768];
  const int tid = threadIdx.x;
  const int lane = tid & 63;
  const int w = tid >> 6;
  const int wm = w >> 1, wn = w & 1;
  const int xcd = blockIdx.x & 7;
  const int idx = blockIdx.x >> 3;
  const int nBase = (idx >> 2) * 128;
  const int mBase = (xcd * 4 + (idx & 3)) * 128;
  const int lr = lane & 15, lk = lane >> 4;
  const int K = 1024;

  const int srow = tid >> 3;
  const int scol = (tid & 7) ^ (srow & 7);
  const int wchunk = tid & 192;

  f32x4 acc[4][4];
#pragma unroll
  for (int i = 0; i < 4; ++i)
#pragma unroll
    for (int j = 0; j < 4; ++j) acc[i][j] = (f32x4){0.f, 0.f, 0.f, 0.f};

  const unsigned short* Ag = A + (size_t)mBase * K;
  const unsigned short* Bg = B + (size_t)nBase * K;

  auto stage = [&](int buf, int kt) {
    unsigned short* Ab = smem + buf * 16384;
    unsigned short* Bb = Ab + 8192;
#pragma unroll
    for (int r = 0; r < 4; ++r) {
      int row = r * 32 + srow;
      gload_lds16(Ag + (size_t)row * K + kt * 64 + scol * 8, &Ab[(r * 256 + wchunk) * 8]);
      gload_lds16(Bg + (size_t)row * K + kt * 64 + scol * 8, &Bb[(r * 256 + wchunk) * 8]);
    }
  };

  stage(0, 0);
  __syncthreads();
  for (int kt = 0; kt < 16; ++kt) {
    int cur = kt & 1;
    if (kt < 15) stage(cur ^ 1, kt + 1);
    const unsigned short* Ac = smem + cur * 16384;
    const unsigned short* Bc = Ac + 8192;
#pragma unroll
    for (int ks = 0; ks < 2; ++ks) {
      short8 a[4], b[4];
#pragma unroll
      for (int mf = 0; mf < 4; ++mf) {
        int row = wm * 64 + mf * 16 + lr;
        int cc = (ks * 4 + lk) ^ (row & 7);
        a[mf] = *(const short8*)&Ac[row * 64 + cc * 8];
      }
#pragma unroll
      for (int nf = 0; nf < 4; ++nf) {
        int row = wn * 64 + nf * 16 + lr;
        int cc = (ks * 4 + lk) ^ (row & 7);
        b[nf] = *(const short8*)&Bc[row * 64 + cc * 8];
      }
#pragma unroll
      for (int mf = 0; mf < 4; ++mf)
#pragma unroll
        for (int nf = 0; nf < 4; ++nf)
          acc[mf][nf] = MFMA16(a[mf], b[nf], acc[mf][nf]);
    }
    __syncthreads();
  }

  float* cst = (float*)smem;
#pragma unroll
  for (int r = 0; r < 4; ++r) {
    __syncthreads();
#pragma unroll
    for (int nf = 0; nf < 4; ++nf) {
      int col = wn * 64 + nf * 16 + lr;
      float bv = bias ? bias[nBase + col] : 0.f;
#pragma unroll
      for (int i = 0; i < 4; ++i)
        cst[(wm * 16 + lk * 4 + i) * 132 + col] = acc[r][nf][i] + bv;
    }
    __syncthreads();
#pragma unroll
    for (int pss = 0; pss < 4; ++pss) {
      int idxq = pss * 256 + tid;
      int rl = idxq >> 5, cq = idxq & 31;
      int ar = mBase + (rl >> 4) * 64 + r * 16 + (rl & 15);
      int cr = permC ? ((ar & 31) * 128 + (ar >> 5)) : ar;
      f32x4 v = *(const f32x4*)&cst[rl * 132 + cq * 4];
      __builtin_nontemporal_store(v, (f32x4*)&C[(size_t)cr * N + nBase + cq * 4]);
    }
  }
}

// ---- persistent recurrence + fused gated proj (round-15 protocol) ---------

struct PParams {
  const float* zx0;
  const unsigned short* whh0;
  const unsigned short* wih1;
  const unsigned short* whh1;
  const float* bsum1;
  const float* cell;
  unsigned short* h0hist;       // [129][32][1024]
  const unsigned short* h1init; // [32][1024]
  unsigned short* outb;         // [128][32][1024]  t-major
  unsigned int* slots0;         // 64 x 32-uint stride (WG-level)
  unsigned int* slots1;         // 128 x 32-uint stride (WG-level)
  unsigned int* queue;
  const unsigned short* embB;
  float* outC;
  int njobs;
};

__device__ __forceinline__ void proj_tile(int j, bool valid, int ltid, char* smbase,
                                          const unsigned short* Aout,
                                          const unsigned short* Bemb, float* C) {
  const int mB = j / 250, nB = j % 250;
  const int mBase = mB * 128, nBase = nB * 128;
  const int lane = ltid & 63;
  const int w4 = ltid >> 6;
  const int wm = w4 >> 1, wn = w4 & 1;
  const int lr = lane & 15, lk = lane >> 4;
  const int srow = ltid >> 3;
  const int scol = (ltid & 7) ^ (srow & 7);
  const int wchunk = ltid & 192;
  unsigned short* smem = (unsigned short*)smbase;

  f32x4 acc[4][4];
#pragma unroll
  for (int i = 0; i < 4; ++i)
#pragma unroll
    for (int q = 0; q < 4; ++q) acc[i][q] = (f32x4){0.f, 0.f, 0.f, 0.f};

  const unsigned short* Ag = Aout + (size_t)mBase * 1024;
  const unsigned short* Bg = Bemb + (size_t)nBase * 1024;

  auto stage = [&](int buf, int kt) {
    if (!valid) return;
    unsigned short* Ab = smem + buf * 16384;
    unsigned short* Bb = Ab + 8192;
#pragma unroll
    for (int r = 0; r < 4; ++r) {
      int row = r * 32 + srow;
      gload_lds16(Ag + (size_t)row * 1024 + kt * 64 + scol * 8, &Ab[(r * 256 + wchunk) * 8]);
      gload_lds16(Bg + (size_t)row * 1024 + kt * 64 + scol * 8, &Bb[(r * 256 + wchunk) * 8]);
    }
  };

  stage(0, 0);
  __syncthreads();
  for (int kt = 0; kt < 16; ++kt) {
    int cur = kt & 1;
    if (kt < 15) stage(cur ^ 1, kt + 1);
    const unsigned short* Ac = smem + cur * 16384;
    const unsigned short* Bc = Ac + 8192;
    if (valid) {
#pragma unroll
      for (int ks = 0; ks < 2; ++ks) {
        short8 a[4], b[4];
#pragma unroll
        for (int mf = 0; mf < 4; ++mf) {
          int row = wm * 64 + mf * 16 + lr;
          int cc = (ks * 4 + lk) ^ (row & 7);
          a[mf] = *(const short8*)&Ac[row * 64 + cc * 8];
        }
#pragma unroll
        for (int nf = 0; nf < 4; ++nf) {
          int row = wn * 64 + nf * 16 + lr;
          int cc = (ks * 4 + lk) ^ (row & 7);
          b[nf] = *(const short8*)&Bc[row * 64 + cc * 8];
        }
#pragma unroll
        for (int mf = 0; mf < 4; ++mf)
#pragma unroll
          for (int nf = 0; nf < 4; ++nf)
            acc[mf][nf] = MFMA16(a[mf], b[nf], acc[mf][nf]);
      }
    }
    __syncthreads();
  }

  float* cst = (float*)smem;
#pragma unroll
  for (int r = 0; r < 4; ++r) {
    __syncthreads();
    if (valid) {
#pragma unroll
      for (int nf = 0; nf < 4; ++nf) {
        int col = wn * 64 + nf * 16 + lr;
#pragma unroll
        for (int i = 0; i < 4; ++i)
          cst[(wm * 16 + lk * 4 + i) * 132 + col] = acc[r][nf][i];
      }
    }
    __syncthreads();
    if (valid) {
#pragma unroll
      for (int pss = 0; pss < 4; ++pss) {
        int idxq = pss * 256 + ltid;
        int rl = idxq >> 5, cq = idxq & 31;
        int ar = mBase + (rl >> 4) * 64 + r * 16 + (rl & 15);
        int cr = (ar & 31) * 128 + (ar >> 5);   // t-major A row -> b-major C row
        f32x4 v = *(const f32x4*)&cst[rl * 132 + cq * 4];
        __builtin_nontemporal_store(v, (f32x4*)&C[(size_t)cr * 32000 + nBase + cq * 4]);
      }
    }
  }
}

__global__ __launch_bounds__(512, 1) void lstm_persist_k(PParams P) {
  const int tid = threadIdx.x;
  const int lane = tid & 63;
  const int w = tid >> 6;
  const int lr = lane & 15, lkk = lane >> 4;

  __shared__ __align__(16) char pool[149504];
  __shared__ int jbase;
  unsigned short* wlds = (unsigned short*)pool;
  float* zraw = (float*)(pool + 131072);

  if (blockIdx.x < 64) {
    // ---------------- layer 0: units u0..u0+15 ----------------
    const int u0 = blockIdx.x * 16;
    const int m = w >> 2;
    const int gp = (w >> 1) & 1;
    const int kh = w & 1;
    const int g0 = gp * 2, g1 = gp * 2 + 1;

    for (int f = w; f < 128; f += 8) {
      int gg = f >> 5, kc = f & 31;
      const unsigned short* src =
          P.whh0 + (size_t)(gg * 1024 + u0 + lr) * 1024 + kc * 32 + lkk * 8;
      *(short8*)&wlds[f * 512 + lane * 8] = *(const short8*)src;
    }
    const int fb = tid >> 3;
    const int jp = tid & 7;
    float creg[2] = {0.f, 0.f};
    if (tid < 256) {
      creg[0] = P.cell[fb * 1024 + u0 + 2 * jp];
      creg[1] = P.cell[fb * 1024 + u0 + 2 * jp + 1];
    }
    __syncthreads();

    for (int i = 0; i < 128; ++i) {
      if (i > 0 && tid < 64) {
        const unsigned tgt = (unsigned)i;
        while (true) {
          unsigned v = ld_u32_dev(&P.slots0[tid * 32]);
          if (__all(v >= tgt)) break;
          __builtin_amdgcn_s_sleep(1);
        }
      }
      __syncthreads();

      float2 zr[4];
      if (tid < 256) {
        const float2* br = (const float2*)(P.zx0 + (size_t)i * 131072 + fb * 4096 + u0 + 2 * jp);
#pragma unroll
        for (int q = 0; q < 4; ++q) zr[q] = br[q * 512];
      }
      f32x4 acc0 = {0.f, 0.f, 0.f, 0.f}, acc1 = {0.f, 0.f, 0.f, 0.f};
      const unsigned short* ap =
          P.h0hist + (size_t)i * 32768 + (size_t)(m * 16 + lr) * 1024 + kh * 512 + lkk * 8;
#pragma unroll
      for (int g4 = 0; g4 < 2; ++g4) {
        short8 a[8];
#pragma unroll
        for (int q = 0; q < 8; ++q) a[q] = *(const short8*)(ap + (g4 * 8 + q) * 32);
#pragma unroll
        for (int q = 0; q < 8; ++q) {
          int kc = kh * 16 + g4 * 8 + q;
          short8 b0 = *(const short8*)&wlds[(g0 * 32 + kc) * 512 + lane * 8];
          short8 b1 = *(const short8*)&wlds[(g1 * 32 + kc) * 512 + lane * 8];
          acc0 = MFMA16(a[q], b0, acc0);
          acc1 = MFMA16(a[q], b1, acc1);
        }
      }
#pragma unroll
      for (int j = 0; j < 4; ++j) {
        zraw[(kh * 32 + m * 16 + lkk * 4 + j) * 72 + g0 * 16 + lr] = acc0[j];
        zraw[(kh * 32 + m * 16 + lkk * 4 + j) * 72 + g1 * 16 + lr] = acc1[j];
      }
      __syncthreads();

      if (tid < 256) {
        unsigned hv = 0;
#pragma unroll
        for (int u = 0; u < 2; ++u) {
          int j = 2 * jp + u;
          float zi = zraw[fb * 72 + j]      + zraw[(32 + fb) * 72 + j]      + ((u == 0) ? zr[0].x : zr[0].y);
          float zf = zraw[fb * 72 + 16 + j] + zraw[(32 + fb) * 72 + 16 + j] + ((u == 0) ? zr[1].x : zr[1].y);
          float zg = zraw[fb * 72 + 32 + j] + zraw[(32 + fb) * 72 + 32 + j] + ((u == 0) ? zr[2].x : zr[2].y);
          float zo = zraw[fb * 72 + 48 + j] + zraw[(32 + fb) * 72 + 48 + j] + ((u == 0) ? zr[3].x : zr[3].y);
          float ii = 1.f / (1.f + __expf(-zi));
          float ff = 1.f / (1.f + __expf(-zf));
          float gg = tanhf(zg);
          float oo = 1.f / (1.f + __expf(-zo));
          float cn = ff * creg[u] + ii * gg;
          creg[u] = cn;
          float hn = oo * tanhf(cn);
          hv |= ((unsigned)f2bf(hn)) << (16 * u);
        }
        st_u32_dev((unsigned*)&P.h0hist[(size_t)(i + 1) * 32768 + fb * 1024 + u0 + 2 * jp], hv);
      }
      __syncthreads();   // vmcnt(0) drain: h stores at coherence point
      if (tid == 0) st_u32_dev(&P.slots0[blockIdx.x * 32], (unsigned)(i + 1));
    }
  } else if (blockIdx.x < 192) {
    // ---------------- layer 1: units u0..u0+7 ----------------
    const int u0 = (blockIdx.x - 64) * 8;
    const int slot = blockIdx.x - 64;
    const int mat = w >> 2;
    const int m = (w >> 1) & 1;
    const int kh = w & 1;

    for (int f = w; f < 128; f += 8) {
      int matf = f >> 6, nt = (f >> 5) & 1, kc = f & 31;
      int rr = nt * 16 + lr;
      int gate = rr >> 3, unit = rr & 7;
      const unsigned short* Wm = matf ? P.whh1 : P.wih1;
      const unsigned short* src =
          Wm + (size_t)(gate * 1024 + u0 + unit) * 1024 + kc * 32 + lkk * 8;
      *(short8*)&wlds[f * 512 + lane * 8] = *(const short8*)src;
    }
    const int fb = tid >> 2;
    const int jp = tid & 3;
    float creg[2] = {0.f, 0.f};
    float brg[4][2];
    if (tid < 128) {
      creg[0] = P.cell[32768 + fb * 1024 + u0 + 2 * jp];
      creg[1] = P.cell[32768 + fb * 1024 + u0 + 2 * jp + 1];
#pragma unroll
      for (int q = 0; q < 4; ++q) {
        brg[q][0] = P.bsum1[q * 1024 + u0 + 2 * jp];
        brg[q][1] = P.bsum1[q * 1024 + u0 + 2 * jp + 1];
      }
    }
    __syncthreads();

    for (int i = 1; i <= 128; ++i) {
      if (tid < 64) {
        const unsigned t0 = (unsigned)i, t1 = (unsigned)(i - 1);
        while (true) {
          bool ok = ld_u32_dev(&P.slots0[tid * 32]) >= t0;
          if (i > 1) {
            ok = ok && ld_u32_dev(&P.slots1[tid * 32]) >= t1
                    && ld_u32_dev(&P.slots1[(tid + 64) * 32]) >= t1;
          }
          if (__all(ok)) break;
          __builtin_amdgcn_s_sleep(2);
        }
      }
      __syncthreads();

      f32x4 acc0 = {0.f, 0.f, 0.f, 0.f}, acc1 = {0.f, 0.f, 0.f, 0.f};
      const unsigned short* ap;
      if (mat == 0) {
        ap = P.h0hist + (size_t)i * 32768 + (size_t)(m * 16 + lr) * 1024 + kh * 512 + lkk * 8;
      } else {
        const unsigned short* h1b =
            (i == 1) ? P.h1init : (P.outb + (size_t)(i - 2) * 32768);
        ap = h1b + (size_t)(m * 16 + lr) * 1024 + kh * 512 + lkk * 8;
      }
#pragma unroll
      for (int g4 = 0; g4 < 2; ++g4) {
        short8 a[8];
#pragma unroll
        for (int q = 0; q < 8; ++q) a[q] = *(const short8*)(ap + (g4 * 8 + q) * 32);
#pragma unroll
        for (int q = 0; q < 8; ++q) {
          int kc = kh * 16 + g4 * 8 + q;
          short8 b0 = *(const short8*)&wlds[(mat * 64 + 0 * 32 + kc) * 512 + lane * 8];
          short8 b1 = *(const short8*)&wlds[(mat * 64 + 1 * 32 + kc) * 512 + lane * 8];
          acc0 = MFMA16(a[q], b0, acc0);
          acc1 = MFMA16(a[q], b1, acc1);
        }
      }
      float* zp = zraw + (mat * 2 + kh) * 1152;
#pragma unroll
      for (int j = 0; j < 4; ++j) {
        zp[(m * 16 + lkk * 4 + j) * 36 + lr] = acc0[j];
        zp[(m * 16 + lkk * 4 + j) * 36 + 16 + lr] = acc1[j];
      }
      __syncthreads();

      if (tid < 128) {
        unsigned hv = 0;
#pragma unroll
        for (int u = 0; u < 2; ++u) {
          int j = 2 * jp + u;
          float z4[4];
#pragma unroll
          for (int q = 0; q < 4; ++q) {
            z4[q] = zraw[fb * 36 + q * 8 + j] + zraw[1152 + fb * 36 + q * 8 + j]
                  + zraw[2304 + fb * 36 + q * 8 + j] + zraw[3456 + fb * 36 + q * 8 + j]
                  + brg[q][u];
          }
          float ii = 1.f / (1.f + __expf(-z4[0]));
          float ff = 1.f / (1.f + __expf(-z4[1]));
          float gg = tanhf(z4[2]);
          float oo = 1.f / (1.f + __expf(-z4[3]));
          float cn = ff * creg[u] + ii * gg;
          creg[u] = cn;
          float hn = oo * tanhf(cn);
          hv |= ((unsigned)f2bf(hn)) << (16 * u);
        }
        st_u32_dev((unsigned*)&P.outb[(size_t)(i - 1) * 32768 + fb * 1024 + u0 + 2 * jp], hv);
      }
      __syncthreads();
      if (tid == 0) st_u32_dev(&P.slots1[slot * 32], (unsigned)i);
    }
  }

  // ---------------- gated proj job loop (2 tiles per WG) ----------------
  while (true) {
    __syncthreads();
    if (tid == 0)
      jbase = (int)__hip_atomic_fetch_add(P.queue, 2u, __ATOMIC_RELAXED,
                                          __HIP_MEMORY_SCOPE_AGENT);
    __syncthreads();
    int base = jbase;
    if (base >= P.njobs) break;
    int j = base + (tid >> 8);
    bool valid = (j < P.njobs);
    int jmax = (base + 1 < P.njobs) ? base + 1 : base;
    int gateMB = jmax / 250;
    if (tid < 64) {
      unsigned tgt = (unsigned)(4 * gateMB + 4);
      if (tgt > 128u) tgt = 128u;
      while (true) {
        bool ok = ld_u32_dev(&P.slots1[tid * 32]) >= tgt &&
                  ld_u32_dev(&P.slots1[(tid + 64) * 32]) >= tgt;
        if (__all(ok)) break;
        __builtin_amdgcn_s_sleep(2);
      }
    }
    __syncthreads();
    proj_tile(j, valid, tid & 255, pool + (tid >> 8) * 65536, P.outb, P.embB, P.outC);
  }
}

// ---------------------------------------------------------------------------

extern "C" void kernel_launch(void* const* d_in, const int* in_sizes, int n_in,
                              void* d_out, int out_size, void* d_ws, size_t ws_size,
                              hipStream_t stream) {
  const int*   x      = (const int*)d_in[0];
  const float* hidden = (const float*)d_in[1];
  const float* cell   = (const float*)d_in[2];
  const int*   target = (const int*)d_in[3];
  const float* emb    = (const float*)d_in[5];
  const float* w_ih   = (const float*)d_in[6];
  const float* w_hh   = (const float*)d_in[7];
  const float* b_ih   = (const float*)d_in[8];
  const float* b_hh   = (const float*)d_in[9];
  float* out = (float*)d_out;
  char* ws = (char*)d_ws;

  // ws layout (bytes)
  unsigned short* emb_bf  = (unsigned short*)(ws);                 // 65,536,000
  unsigned short* wih_bf  = (unsigned short*)(ws + 65536000);      // 16,777,216 (L0+L1)
  unsigned short* whh_bf  = (unsigned short*)(ws + 82313216);      // 16,777,216 (L0+L1)
  float*          bsum    = (float*)(ws + 99090432);               //     32,768
  unsigned short* outb    = (unsigned short*)(ws + 99123200);      //  8,388,608 (t-major)
  unsigned int*   barmem  = (unsigned int*)(ws + 107511808);       //     32,768
  unsigned short* h1init  = (unsigned short*)(ws + 107544576);     //     65,536

  const size_t WS_NEED = 107610112ull + 67108864ull + 8454144ull;  // 183,173,120
  const bool rich = (ws_size >= WS_NEED);
  float*          zx0    = rich ? (float*)(ws + 107610112)
                                : (float*)d_out;
  unsigned short* xseq   = rich ? (unsigned short*)d_out
                                : (unsigned short*)((char*)d_out + 67108864);
  unsigned short* h0hist = rich ? (unsigned short*)(ws + 174718976)
                                : (unsigned short*)((char*)d_out + 75497472);

  hipMemsetAsync(barmem, 0, 32768, stream);
  cvt_bf16_k<<<2048, 256, 0, stream>>>(emb, emb_bf, 8192000);
  cvt_bf16_k<<<2048, 256, 0, stream>>>(w_ih, wih_bf, 2097152);     // both layers
  cvt_bf16_k<<<2048, 256, 0, stream>>>(w_hh, whh_bf, 2097152);     // both layers
  init_small_k<<<96, 256, 0, stream>>>(hidden, b_ih, b_hh, h0hist, h1init, bsum);
  embed_k<<<4096, 256, 0, stream>>>(x, target, emb, xseq);

  // Zx0 = x_seq @ w_ih[0]^T + bsum0   [4096 x 4096]
  gemm_bf16_k<<<1024, 256, 0, stream>>>(xseq, wih_bf, zx0, bsum, 4096, 0);

  PParams pp;
  pp.zx0 = zx0;
  pp.whh0 = whh_bf;
  pp.wih1 = wih_bf + 4194304;
  pp.whh1 = whh_bf + 4194304;
  pp.bsum1 = bsum + 4096;
  pp.cell = cell;
  pp.h0hist = h0hist;
  pp.h1init = h1init;
  pp.outb = outb;
  pp.slots0 = barmem;              // 64 slots x 128B (WG-level)
  pp.slots1 = barmem + 2048;       // 128 slots x 128B (WG-level)
  pp.queue = barmem + 6144;
  pp.embB = emb_bf;
  pp.outC = out;
  pp.njobs = rich ? 8000 : 0;
  lstm_persist_k<<<rich ? 256 : 192, 512, 0, stream>>>(pp);

  if (!rich) {
    gemm_bf16_k<<<8000, 256, 0, stream>>>(outb, emb_bf, out, nullptr, 32000, 1);
  }
}